// Round 6
// baseline (211.336 us; speedup 1.0000x reference)
//
#include <hip/hip_runtime.h>
#include <hip/hip_bf16.h>
#include <math.h>

typedef __attribute__((ext_vector_type(4))) float f32x4;
typedef __attribute__((ext_vector_type(8))) short bf16x8;

#define N_ROWS 8192
#define D 256
#define MSHIFT 16.0f
#define NKB 4
#define KRANGE (N_ROWS / NKB)     // 2048
#define NSTEP (KRANGE / 32)       // 64

__device__ __forceinline__ unsigned short f2bf(float f) {
    unsigned int u = __float_as_uint(f);
    unsigned int r = u + 0x7FFFu + ((u >> 16) & 1u);
    return (unsigned short)(r >> 16);
}

__device__ __forceinline__ float breduce_sum256(float v, float* sb) {
#pragma unroll
    for (int off = 32; off; off >>= 1) v += __shfl_down(v, off);
    int wid = threadIdx.x >> 6;
    __syncthreads();
    if ((threadIdx.x & 63) == 0) sb[wid] = v;
    __syncthreads();
    return sb[0] + sb[1] + sb[2] + sb[3];
}

__device__ __forceinline__ void dma16(const void* g, void* l) {
    __builtin_amdgcn_global_load_lds(
        (const __attribute__((address_space(1))) unsigned int*)g,
        (__attribute__((address_space(3))) unsigned int*)l, 16, 0, 0);
}

__device__ __forceinline__ bf16x8 adj2bf(int4 a, int4 b) {
    bf16x8 r;
    r[0] = a.x ? (short)0x3F80 : (short)0;
    r[1] = a.y ? (short)0x3F80 : (short)0;
    r[2] = a.z ? (short)0x3F80 : (short)0;
    r[3] = a.w ? (short)0x3F80 : (short)0;
    r[4] = b.x ? (short)0x3F80 : (short)0;
    r[5] = b.y ? (short)0x3F80 : (short)0;
    r[6] = b.z ? (short)0x3F80 : (short)0;
    r[7] = b.w ? (short)0x3F80 : (short)0;
    return r;
}

// K2: M2[k][j] = sum_m W_gcn[k][m] * W_att[m+1][j]
__global__ void k_M2(const float* __restrict__ Wg, const float* __restrict__ Wa,
                     float* __restrict__ M2) {
    int k = blockIdx.x, t = threadIdx.x;
    float acc = 0.f;
#pragma unroll 8
    for (int m = 0; m < 255; ++m)
        acc += Wg[k * 255 + m] * Wa[(m + 1) * 256 + t];
    M2[k * 256 + t] = acc;
}

// K3: fused logmap0 + h-GEMV + attention-weight exp + direct GT write
__global__ void k_h2(const float* __restrict__ x, const float* __restrict__ M2,
                     const float* __restrict__ aatt,
                     unsigned short* __restrict__ wbf, unsigned short* __restrict__ GT) {
    __shared__ float sb[4];
    __shared__ float Ls[8][256];
    int i0 = blockIdx.x * 8, t = threadIdx.x;
#pragma unroll
    for (int r = 0; r < 8; ++r) {
        float xv = x[(size_t)(i0 + r) * D + t];
        float yv = (t >= 1) ? xv : 0.f;
        float ss = breduce_sum256(yv * yv, sb);
        float ynorm = fmaxf(sqrtf(ss), 1e-15f);
        float x0 = x[(size_t)(i0 + r) * D];
        float th = fmaxf(x0, 1.f + 1e-7f);
        float al = acoshf(th);
        Ls[r][t] = (t >= 1) ? (al * yv / ynorm) : 0.f;
    }
    __syncthreads();
    float acc[8] = {0.f, 0.f, 0.f, 0.f, 0.f, 0.f, 0.f, 0.f};
#pragma unroll 4
    for (int k = 0; k < 255; ++k) {
        float m2 = M2[k * 256 + t];
#pragma unroll
        for (int r = 0; r < 8; ++r) acc[r] += Ls[r][k + 1] * m2;
    }
    float a2 = aatt[256 + t];
    float wr[8];
#pragma unroll
    for (int r = 0; r < 8; ++r) {
        float s = breduce_sum256(acc[r] * a2, sb);
        wr[r] = expf(s - MSHIFT);
        if (t == r) wbf[i0 + r] = f2bf(wr[r]);
    }
    bf16x8 g;
#pragma unroll
    for (int r = 0; r < 8; ++r) g[r] = (short)f2bf(acc[r] * wr[r]);
    *(bf16x8*)(GT + (size_t)t * N_ROWS + i0) = g;
}

// K6: masked GEMM, adj read once in-loop. BM=64, BN=256, BK=32.
// Triple-buffered LDS (depth-3 pipeline), ONE barrier/step, counted vmcnt(6).
// Buffer-t reuse hazard: STAGE(t+2) clobbers buffer (t-1)%3, but it is issued
// after barrier t, and every wave consumed buffer (t-1) (MFMA data in regs)
// before reaching barrier t -> safe.
__global__ void __launch_bounds__(256, 2)
k_attadj(const int* __restrict__ adj, const unsigned short* __restrict__ GT,
         const unsigned short* __restrict__ wbf, float* __restrict__ part,
         float* __restrict__ rspart) {
    __shared__ __align__(16) char bufA[3 * 8192];   // 3 x (64 rows x 32 ints)
    __shared__ __align__(16) char bufB[3 * 16384];  // 3 x (256 cols x 32 bf16)
    __shared__ __align__(16) char wlds[4096];       // KRANGE bf16 weights
    const int tid = threadIdx.x;
    const int rb = blockIdx.x & 127;
    const int kb = blockIdx.x >> 7;
    const int i0 = rb * 64;
    const int kbeg = kb * KRANGE;
    const int w = tid >> 6, l = tid & 63;
    const int lr = l & 15, lq = l >> 4;

    // ---- DMA sources (pre-swizzled global addresses; LDS dests linear)
    const int a0 = w * 2, a1 = a0 + 1;
    const int ra0 = a0 * 8 + (l >> 3), ra1 = a1 * 8 + (l >> 3);
    const int pgA = (l & 7) ^ ((l >> 3) & 7);
    const int* srcA0 = adj + (size_t)(i0 + ra0) * N_ROWS + kbeg + pgA * 4;
    const int* srcA1 = adj + (size_t)(i0 + ra1) * N_ROWS + kbeg + pgA * 4;
    const int bswz = ((l >> 2) & 3) ^ ((l >> 4) & 3);
    const unsigned short* srcB0 = GT + (size_t)((w * 4 + 0) * 16 + (l >> 2)) * N_ROWS + kbeg + ((l & 3) ^ bswz) * 8;
    const unsigned short* srcB1 = GT + (size_t)((w * 4 + 1) * 16 + (l >> 2)) * N_ROWS + kbeg + ((l & 3) ^ bswz) * 8;
    const unsigned short* srcB2 = GT + (size_t)((w * 4 + 2) * 16 + (l >> 2)) * N_ROWS + kbeg + ((l & 3) ^ bswz) * 8;
    const unsigned short* srcB3 = GT + (size_t)((w * 4 + 3) * 16 + (l >> 2)) * N_ROWS + kbeg + ((l & 3) ^ bswz) * 8;

#define STAGE(t_, bi_) do {                                        \
        const int koff_ = (t_) * 32;                               \
        char* bA_ = bufA + (bi_) * 8192;                           \
        char* bB_ = bufB + (bi_) * 16384;                          \
        dma16(srcA0 + koff_, bA_ + a0 * 1024);                     \
        dma16(srcA1 + koff_, bA_ + a1 * 1024);                     \
        dma16(srcB0 + koff_, bB_ + (w * 4 + 0) * 1024);            \
        dma16(srcB1 + koff_, bB_ + (w * 4 + 1) * 1024);            \
        dma16(srcB2 + koff_, bB_ + (w * 4 + 2) * 1024);            \
        dma16(srcB3 + koff_, bB_ + (w * 4 + 3) * 1024);            \
    } while (0)

    f32x4 zero4 = {0.f, 0.f, 0.f, 0.f};
    f32x4 acc[4][4], acc_rs[4];
#pragma unroll
    for (int m = 0; m < 4; ++m) {
        acc_rs[m] = zero4;
#pragma unroll
        for (int n = 0; n < 4; ++n) acc[m][n] = zero4;
    }

    // prologue: stage steps 0,1 + weight tile (13 DMAs outstanding)
    STAGE(0, 0);
    dma16(wbf + kbeg + w * 512 + l * 8, wlds + w * 1024);
    STAGE(1, 1);

    // read-side swizzled offsets (lane-constant)
    const int gA0 = lr * 128 + (((2 * lq) ^ (lr & 7)) << 4);
    const int gA1 = lr * 128 + (((2 * lq + 1) ^ (lr & 7)) << 4);
    const int gB = lr * 64 + ((lq ^ (lr & 3) ^ ((lr >> 2) & 3)) << 4);

    int cb = 0;   // buffer index for step t
    for (int t = 0; t < NSTEP; ++t) {
        if (t == NSTEP - 1) asm volatile("s_waitcnt vmcnt(0)" ::: "memory");
        else                asm volatile("s_waitcnt vmcnt(6)" ::: "memory");
        __builtin_amdgcn_sched_barrier(0);
        __builtin_amdgcn_s_barrier();
        __builtin_amdgcn_sched_barrier(0);
        if (t + 2 < NSTEP) {
            int sb_ = (cb == 0) ? 2 : cb - 1;    // (t+2)%3
            STAGE(t + 2, sb_);
        }
        const char* bA = bufA + cb * 8192;
        const char* bB = bufB + cb * 16384;

        bf16x8 wf = {0, 0, 0, 0, 0, 0, 0, 0};
        if (lr == 0) wf = *(const bf16x8*)(wlds + t * 64 + lq * 16);

        bf16x8 af[4];
#pragma unroll
        for (int m = 0; m < 4; ++m) {
            int4 u = *(const int4*)(bA + m * 2048 + gA0);
            int4 v = *(const int4*)(bA + m * 2048 + gA1);
            af[m] = adj2bf(u, v);
        }
#pragma unroll
        for (int n = 0; n < 4; ++n) {
            bf16x8 bf = *(const bf16x8*)(bB + w * 4096 + n * 1024 + gB);
#pragma unroll
            for (int m = 0; m < 4; ++m)
                acc[m][n] = __builtin_amdgcn_mfma_f32_16x16x32_bf16(af[m], bf, acc[m][n], 0, 0, 0);
        }
#pragma unroll
        for (int m = 0; m < 4; ++m)
            acc_rs[m] = __builtin_amdgcn_mfma_f32_16x16x32_bf16(af[m], wf, acc_rs[m], 0, 0, 0);
        cb = (cb == 2) ? 0 : cb + 1;
    }
#undef STAGE

    // rowsum (col 0 of acc_rs; waves identical, wave 0 writes)
    if (w == 0 && lr == 0) {
#pragma unroll
        for (int m = 0; m < 4; ++m)
#pragma unroll
            for (int v = 0; v < 4; ++v)
                rspart[(size_t)kb * N_ROWS + i0 + m * 16 + lq * 4 + v] = acc_rs[m][v];
    }

    // C write (layout: col=lane&15, row=(lane>>4)*4+reg)
    float* pbase = part + (size_t)kb * N_ROWS * D;
#pragma unroll
    for (int m = 0; m < 4; ++m)
#pragma unroll
        for (int n = 0; n < 4; ++n) {
            int orow = i0 + m * 16 + lq * 4;
            int ocol = (w << 6) + (n << 4) + lr;
            float* op = pbase + (size_t)orow * D + ocol;
#pragma unroll
            for (int v = 0; v < 4; ++v) op[(size_t)v * D] = acc[m][n][v];
        }
}

// K7: split-K reduce + epilogue (divide, elu, proj, logmap0, sigmoid, expmap0)
__global__ void k_final3(const float* __restrict__ part, const float* __restrict__ rspart,
                         float* __restrict__ out) {
    __shared__ float sb[4];
    int row = blockIdx.x, t = threadIdx.x;
    float raw = 0.f, rs = 0.f;
#pragma unroll
    for (int kbi = 0; kbi < NKB; ++kbi) {
        raw += part[((size_t)kbi * N_ROWS + row) * D + t];
        rs += rspart[(size_t)kbi * N_ROWS + row];
    }
    float hp = raw / rs;
    float ey = 0.f;
    if (t >= 1) ey = (hp > 0.f) ? hp : expm1f(hp);
    float ss = breduce_sum256(ey * ey, sb);
    float x0 = sqrtf(1.f + ss);
    float th = fmaxf(x0, 1.f + 1e-7f);
    float al = acoshf(th);
    float yn = fmaxf(sqrtf(ss), 1e-15f);
    float u = (t >= 1) ? (al * ey / yn) : 0.f;
    float s = 1.f / (1.f + expf(-u));
    float s2 = (t >= 1) ? s * s : 0.f;
    float ssn = breduce_sum256(s2, sb);
    float xn = fmaxf(sqrtf(ssn), 1e-15f);
    float sh = sinhf(xn);
    float yf = (t >= 1) ? (sh * s / xn) : 0.f;
    float sy = breduce_sum256(yf * yf, sb);
    float res = (t == 0) ? sqrtf(1.f + sy) : yf;
    out[(size_t)row * D + t] = res;
}

extern "C" void kernel_launch(void* const* d_in, const int* in_sizes, int n_in,
                              void* d_out, int out_size, void* d_ws, size_t ws_size,
                              hipStream_t stream) {
    const float* x    = (const float*)d_in[0];
    const int*   adj  = (const int*)d_in[1];
    const float* Wg   = (const float*)d_in[3];
    const float* Wa   = (const float*)d_in[4];
    const float* aatt = (const float*)d_in[5];
    float* out = (float*)d_out;

    char* wsb = (char*)d_ws;
    float*          M2     = (float*)(wsb);                      // 256 KB
    unsigned short* GT     = (unsigned short*)(wsb + 0x0040000); // 4 MB
    unsigned short* wbf    = (unsigned short*)(wsb + 0x0440000); // 16 KB
    float*          rspart = (float*)(wsb + 0x0448000);          // 128 KB
    float*          part   = (float*)(wsb + 0x0480000);          // 32 MB

    k_M2<<<255, 256, 0, stream>>>(Wg, Wa, M2);
    k_h2<<<N_ROWS / 8, 256, 0, stream>>>(x, M2, aatt, wbf, GT);
    k_attadj<<<128 * NKB, 256, 0, stream>>>(adj, GT, wbf, part, rspart);
    k_final3<<<N_ROWS, 256, 0, stream>>>(part, rspart, out);
}